// Round 6
// baseline (357.837 us; speedup 1.0000x reference)
//
#include <hip/hip_runtime.h>
#include <hip/hip_bf16.h>
#include <stdint.h>

// Problem constants (fixed by the reference)
#define NTOK 4096
#define HID  512
#define INSZ 1024   // E + H
#define KIN  1536   // INSZ + HID (fused LSTM input: x | h)
#define KCAT 64
#define CCH  128
#define MCELL 4
#define G4H  2048   // 4*H

typedef unsigned short u16;
typedef __bf16 bf16x8 __attribute__((ext_vector_type(8)));
typedef float  f32x4  __attribute__((ext_vector_type(4)));

__device__ __forceinline__ u16 f2bf(float f) {
    unsigned u = __float_as_uint(f);
    u += 0x7fffu + ((u >> 16) & 1u);   // RTNE
    return (u16)(u >> 16);
}
__device__ __forceinline__ float bf2f(u16 v) {
    return __uint_as_float(((unsigned)v) << 16);
}
__device__ __forceinline__ void store_bf4(u16* p, float4 v) {
    ushort4 r;
    r.x = f2bf(v.x); r.y = f2bf(v.y); r.z = f2bf(v.z); r.w = f2bf(v.w);
    *reinterpret_cast<ushort4*>(p) = r;
}

// meta layout (ints): [0..3] ci padded cnt, [4..7] ci padded off,
// [8..71] cat padded cnt, [72..135] cat padded off, [136..263] tile->cat LUT
// ---------------------------------------------------------------------------
// Dispatch 0: pack Wb (W_ih|W_hh -> bf16) + Wlin (bf16) + build_perm (last blk)
// ---------------------------------------------------------------------------
#define P0_W 8192
#define P0_L 2731
__global__ __launch_bounds__(192) void pack_all(
    const float* __restrict__ Wih, const float* __restrict__ Whh,
    const float* __restrict__ W_lin,
    const int* __restrict__ ci, const int* __restrict__ cat,
    u16* __restrict__ Wb, u16* __restrict__ Wlin,
    int* __restrict__ meta, int* __restrict__ perm_ci, int* __restrict__ perm_cat)
{
    int b = blockIdx.x;
    int tid = threadIdx.x;
    int c = tid * 8;
    if (b < P0_W) {                       // Wb row (m*2048+j)
        int m = b >> 11, j = b & 2047;
        const float* src = (c < INSZ) ? (Wih + ((size_t)m * G4H + j) * INSZ + c)
                                      : (Whh + ((size_t)m * G4H + j) * HID + (c - INSZ));
        u16* dst = Wb + (size_t)b * KIN + c;
        store_bf4(dst, *(const float4*)src);
        store_bf4(dst + 4, *(const float4*)(src + 4));
    } else if (b < P0_W + P0_L) {         // Wlin: 3 rows of 512 per block
        int row = (b - P0_W) * 3 + (c >> 9);
        int col = c & 511;
        if (row >= KCAT * CCH) return;
        const float* src = W_lin + (size_t)row * HID + col;
        u16* dst = Wlin + (size_t)row * HID + col;
        store_bf4(dst, *(const float4*)src);
        store_bf4(dst + 4, *(const float4*)(src + 4));
    } else {                              // build_perm (single block)
        __shared__ int cnt_ci[MCELL], cur_ci[MCELL];
        __shared__ int cnt_cat[KCAT], cur_cat[KCAT];
        if (tid < MCELL) cnt_ci[tid] = 0;
        if (tid < KCAT)  cnt_cat[tid] = 0;
        __syncthreads();
        for (int t = tid; t < NTOK; t += 192) {
            atomicAdd(&cnt_ci[ci[t]], 1);
            atomicAdd(&cnt_cat[cat[t]], 1);
        }
        __syncthreads();
        if (tid == 0) {
            int off = 0;
            for (int m = 0; m < MCELL; ++m) {
                int p = (cnt_ci[m] + 127) & ~127;
                meta[m] = p; meta[4 + m] = off; cur_ci[m] = off; off += p;
            }
            off = 0;
            for (int i = 0; i < 128; ++i) meta[136 + i] = -1;
            for (int k = 0; k < KCAT; ++k) {
                int p = (cnt_cat[k] + 63) & ~63;
                meta[8 + k] = p; meta[72 + k] = off; cur_cat[k] = off;
                for (int i = 0; i < p / 64; ++i) meta[136 + off / 64 + i] = k;
                off += p;
            }
        }
        __syncthreads();
        for (int i = tid; i < 4608; i += 192) perm_ci[i] = -1;
        for (int i = tid; i < 8192; i += 192) perm_cat[i] = -1;
        __syncthreads();
        for (int t = tid; t < NTOK; t += 192) {
            int s = atomicAdd(&cur_ci[ci[t]], 1);
            perm_ci[s] = t;
            int sc = atomicAdd(&cur_cat[cat[t]], 1);
            perm_cat[sc] = t;
        }
    }
}

// ---------------------------------------------------------------------------
// Dispatch 1: slot-ordered packs (need perm): A_pack (ci-slot order, also
// builds inv_ci) and et_s (cat-slot order).
// ---------------------------------------------------------------------------
#define P1_A 4608
#define P1_E 2731
__global__ __launch_bounds__(192) void pack_slots(
    const float* __restrict__ x, const float* __restrict__ h,
    const float* __restrict__ et,
    const int* __restrict__ perm_ci, const int* __restrict__ perm_cat,
    u16* __restrict__ A_pack, u16* __restrict__ et_s, int* __restrict__ inv_ci)
{
    int b = blockIdx.x;
    int tid = threadIdx.x;
    int c = tid * 8;
    if (b < P1_A) {                       // A row, ci-slot order
        int t = perm_ci[b];
        if (tid == 0 && t >= 0) inv_ci[t] = b;
        u16* dst = A_pack + (size_t)b * KIN + c;
        if (t < 0) {
            *reinterpret_cast<int4*>(dst) = make_int4(0, 0, 0, 0);
            return;
        }
        const float* src = (c < INSZ) ? (x + (size_t)t * INSZ + c)
                                      : (h + (size_t)t * HID + (c - INSZ));
        store_bf4(dst, *(const float4*)src);
        store_bf4(dst + 4, *(const float4*)(src + 4));
    } else {                              // et_s: 3 rows of 512 per block
        int row = (b - P1_A) * 3 + (c >> 9);
        int col = c & 511;
        if (row >= 8192) return;
        int t = perm_cat[row];
        u16* dst = et_s + (size_t)row * HID + col;
        if (t < 0) {
            *reinterpret_cast<int4*>(dst) = make_int4(0, 0, 0, 0);
            return;
        }
        const float* src = et + (size_t)t * HID + col;
        store_bf4(dst, *(const float4*)src);
        store_bf4(dst + 4, *(const float4*)(src + 4));
    }
}

// ---------------------------------------------------------------------------
// Dispatch 2: barrier-free wave-GEMM. One wave (64 thr) = one 64x64 tile.
// NO LDS, NO __syncthreads: MFMA fragments are 16 B/lane contiguous in K, so
// they load directly from packed bf16 global via per-lane dwordx4 through
// L1/L2, 2-deep ping-pong prefetch. Every wave is an independent memory
// stream -> fine-grained vmcnt pipelining the barrier structure couldn't do.
// ---------------------------------------------------------------------------
template<int NSTEP>
__device__ __forceinline__ void mma_tile64(
    const u16* __restrict__ Abase, const u16* __restrict__ Bbase,
    int kstride, int l15, int qd, f32x4 acc[4][4])
{
    const u16* pa[4]; const u16* pb[4];
    #pragma unroll
    for (int t = 0; t < 4; ++t) {
        pa[t] = Abase + (size_t)(t * 16 + l15) * kstride + qd * 8;
        pb[t] = Bbase + (size_t)(t * 16 + l15) * kstride + qd * 8;
    }
    bf16x8 fa[2][4], fb[2][4];
    #pragma unroll
    for (int t = 0; t < 4; ++t) {
        fa[0][t] = *reinterpret_cast<const bf16x8*>(pa[t]);
        fb[0][t] = *reinterpret_cast<const bf16x8*>(pb[t]);
    }
    #pragma unroll 2
    for (int s = 0; s < NSTEP; ++s) {
        int cur = s & 1, nxt = cur ^ 1;
        if (s + 1 < NSTEP) {
            int ko = (s + 1) * 32;
            #pragma unroll
            for (int t = 0; t < 4; ++t) {
                fa[nxt][t] = *reinterpret_cast<const bf16x8*>(pa[t] + ko);
                fb[nxt][t] = *reinterpret_cast<const bf16x8*>(pb[t] + ko);
            }
        }
        #pragma unroll
        for (int i = 0; i < 4; ++i)
            #pragma unroll
            for (int j = 0; j < 4; ++j)
                acc[i][j] = __builtin_amdgcn_mfma_f32_16x16x32_bf16(
                    fa[cur][i], fb[cur][j], acc[i][j], 0, 0, 0);
    }
}

__global__ __launch_bounds__(64, 2) void wave_gemm(
    const u16* __restrict__ A_pack,   // [4608][1536] ci-slot order
    const u16* __restrict__ Wb,       // [4][2048][1536]
    const u16* __restrict__ Wlin,     // [64][128][512]
    const u16* __restrict__ et_s,     // [8192][512] cat-slot order
    const float* __restrict__ b_lin,  // [64,128]
    const int* __restrict__ meta,
    const int* __restrict__ perm_cat,
    u16* __restrict__ gates,          // [4608][2048] bf16, slot order
    float* __restrict__ out)          // log_odds at out[0..N*128)
{
    int lane = threadIdx.x;
    int qd = lane >> 4, l15 = lane & 15;

    f32x4 acc[4][4];
    #pragma unroll
    for (int i = 0; i < 4; ++i)
        #pragma unroll
        for (int j = 0; j < 4; ++j)
            acc[i][j] = (f32x4){0.f, 0.f, 0.f, 0.f};

    if (blockIdx.z == 0) {
        // ---------------- gates: row-slot tile x (<72), col tile y (<32) ----
        if (blockIdx.x >= 72) return;
        int r0 = blockIdx.x * 64;
        int m = -1;
        #pragma unroll
        for (int mm = 0; mm < MCELL; ++mm)
            if (r0 >= meta[4 + mm] && r0 < meta[4 + mm] + meta[mm]) m = mm;
        if (m < 0) return;
        int n0 = blockIdx.y * 64;

        mma_tile64<KIN / 32>(A_pack + (size_t)r0 * KIN,
                             Wb + ((size_t)m * G4H + n0) * KIN,
                             KIN, l15, qd, acc);

        #pragma unroll
        for (int ti = 0; ti < 4; ++ti)
            #pragma unroll
            for (int tj = 0; tj < 4; ++tj) {
                int gcol = n0 + tj * 16 + l15;
                #pragma unroll
                for (int r = 0; r < 4; ++r) {
                    int grow = r0 + ti * 16 + qd * 4 + r;
                    gates[(size_t)grow * G4H + gcol] = f2bf(acc[ti][tj][r]);
                }
            }
    } else {
        // ---------------- log_odds: row-tile x (<128), col half y (<2) ------
        if (blockIdx.y >= 2) return;
        int rtl = blockIdx.x;
        int k = meta[136 + rtl];
        if (k < 0) return;
        int r0 = rtl * 64;
        int n0 = blockIdx.y * 64;

        mma_tile64<HID / 32>(et_s + (size_t)r0 * HID,
                             Wlin + ((size_t)k * CCH + n0) * HID,
                             HID, l15, qd, acc);

        #pragma unroll
        for (int ti = 0; ti < 4; ++ti)
            #pragma unroll
            for (int tj = 0; tj < 4; ++tj) {
                int n = n0 + tj * 16 + l15;
                float bias = b_lin[k * CCH + n];
                #pragma unroll
                for (int r = 0; r < 4; ++r) {
                    int slot = r0 + ti * 16 + qd * 4 + r;
                    int t = perm_cat[slot];
                    if (t >= 0)
                        out[(size_t)t * CCH + n] = acc[ti][tj][r] + bias;
                }
            }
    }
}

// ---------------------------------------------------------------------------
// Dispatch 3: LSTM pointwise epilogue (token-indexed via inverse slot map).
// ---------------------------------------------------------------------------
__global__ __launch_bounds__(256) void lstm_epilogue(
    const u16* __restrict__ gates,    // [4608][2048] bf16, slot order
    const int* __restrict__ meta,
    const int* __restrict__ inv_ci,
    const float* __restrict__ c,
    const float* __restrict__ b_ih,   // [4,2048]
    const float* __restrict__ b_hh,   // [4,2048]
    float* __restrict__ out)
{
    int idx = blockIdx.x * 256 + threadIdx.x;   // [0, N*512)
    int t = idx >> 9;
    int hh = idx & 511;
    int s = inv_ci[t];
    int m = (s >= meta[5]) + (s >= meta[6]) + (s >= meta[7]);

    const u16* g = gates + (size_t)s * G4H;
    const float* bi = b_ih + (size_t)m * G4H;
    const float* bh = b_hh + (size_t)m * G4H;
    float gi = bf2f(g[hh])        + bi[hh]        + bh[hh];
    float gf = bf2f(g[512 + hh])  + bi[512 + hh]  + bh[512 + hh];
    float gg = bf2f(g[1024 + hh]) + bi[1024 + hh] + bh[1024 + hh];
    float go = bf2f(g[1536 + hh]) + bi[1536 + hh] + bh[1536 + hh];

    float si = 1.f / (1.f + __expf(-gi));
    float sf = 1.f / (1.f + __expf(-gf));
    float so = 1.f / (1.f + __expf(-go));
    float ct = c[(size_t)t * HID + hh];
    float c2 = sf * ct + si * tanhf(gg);
    float h2 = so * tanhf(c2);

    const size_t o_h2 = (size_t)NTOK * CCH;
    const size_t o_c2 = o_h2 + (size_t)NTOK * HID;
    out[o_h2 + (size_t)t * HID + hh] = h2;
    out[o_c2 + (size_t)t * HID + hh] = c2;
}

// ---------------------------------------------------------------------------
extern "C" void kernel_launch(void* const* d_in, const int* in_sizes, int n_in,
                              void* d_out, int out_size, void* d_ws, size_t ws_size,
                              hipStream_t stream) {
    const float* et    = (const float*)d_in[0];
    const float* x     = (const float*)d_in[1];
    const float* h     = (const float*)d_in[2];
    const float* c     = (const float*)d_in[3];
    const int*   cat   = (const int*)d_in[4];
    const int*   ci    = (const int*)d_in[5];
    const float* W_lin = (const float*)d_in[6];
    const float* b_lin = (const float*)d_in[7];
    const float* W_ih  = (const float*)d_in[8];
    const float* W_hh  = (const float*)d_in[9];
    const float* b_ih  = (const float*)d_in[10];
    const float* b_hh  = (const float*)d_in[11];
    float* out = (float*)d_out;

    char* ws = (char*)d_ws;
    int* meta     = (int*)ws;                         // 512 ints (incl. LUT)
    int* perm_ci  = (int*)(ws + 2048);                // 4608 ints -> 20480
    int* perm_cat = (int*)(ws + 20480);               // 8192 ints -> 53248
    int* inv_ci   = (int*)(ws + 53248);               // 4096 ints -> 69632
    u16* A_pack   = (u16*)(ws + 69632);                          // 14155776
    u16* Wb       = (u16*)(ws + 69632 + 14155776);               // 25165824
    u16* Wlin     = (u16*)(ws + 69632 + 14155776 + 25165824);    // 8388608
    u16* et_s     = (u16*)(ws + 69632 + 14155776 + 25165824 + 8388608);  // 8388608
    u16* gates    = (u16*)(ws + 69632 + 14155776 + 25165824 + 8388608 + 8388608);
    // total ws use ~71.6 MB

    pack_all<<<P0_W + P0_L + 1, 192, 0, stream>>>(W_ih, W_hh, W_lin, ci, cat,
                                                  Wb, Wlin, meta, perm_ci, perm_cat);

    pack_slots<<<P1_A + P1_E, 192, 0, stream>>>(x, h, et, perm_ci, perm_cat,
                                                A_pack, et_s, inv_ci);

    dim3 ggrid(128, 32, 2);  // z=0: gates (x<72, y<32); z=1: logodds (x<128, y<2)
    wave_gemm<<<ggrid, 64, 0, stream>>>(A_pack, Wb, Wlin, et_s, b_lin, meta,
                                        perm_cat, gates, out);

    lstm_epilogue<<<(NTOK * HID) / 256, 256, 0, stream>>>(gates, meta, inv_ci, c,
                                                          b_ih, b_hh, out);
}

// Round 7
// 258.822 us; speedup vs baseline: 1.3826x; 1.3826x over previous
//
#include <hip/hip_runtime.h>
#include <hip/hip_bf16.h>
#include <stdint.h>

// Problem constants (fixed by the reference)
#define NTOK 4096
#define HID  512
#define INSZ 1024   // E + H
#define KIN  1536   // INSZ + HID (fused LSTM input: x | h)
#define KSEG 768    // K-split half
#define KCAT 64
#define CCH  128
#define MCELL 4
#define G4H  2048   // 4*H

typedef unsigned short u16;
typedef __bf16 bf16x8 __attribute__((ext_vector_type(8)));
typedef float  f32x4  __attribute__((ext_vector_type(4)));

__device__ __forceinline__ u16 f2bf(float f) {
    unsigned u = __float_as_uint(f);
    u += 0x7fffu + ((u >> 16) & 1u);   // RTNE
    return (u16)(u >> 16);
}
__device__ __forceinline__ float bf2f(u16 v) {
    return __uint_as_float(((unsigned)v) << 16);
}
__device__ __forceinline__ void store_bf4(u16* p, float4 v) {
    ushort4 r;
    r.x = f2bf(v.x); r.y = f2bf(v.y); r.z = f2bf(v.z); r.w = f2bf(v.w);
    *reinterpret_cast<ushort4*>(p) = r;
}
__device__ __forceinline__ void gl16(const u16* g, u16* l) {
    __builtin_amdgcn_global_load_lds((const __attribute__((address_space(1))) void*)g,
                                     (__attribute__((address_space(3))) void*)l, 16, 0, 0);
}

// meta layout (ints): [0..3] ci padded cnt, [4..7] ci padded off,
// [8..71] cat padded cnt, [72..135] cat padded off, [136..263] tile->cat LUT
// ---------------------------------------------------------------------------
// Dispatch 0: pack Wb (W_ih|W_hh -> bf16) + Wlin (bf16) + build_perm (last blk)
// ---------------------------------------------------------------------------
#define P0_W 8192
#define P0_L 2731
__global__ __launch_bounds__(192) void pack_all(
    const float* __restrict__ Wih, const float* __restrict__ Whh,
    const float* __restrict__ W_lin,
    const int* __restrict__ ci, const int* __restrict__ cat,
    u16* __restrict__ Wb, u16* __restrict__ Wlin,
    int* __restrict__ meta, int* __restrict__ perm_ci, int* __restrict__ perm_cat)
{
    int b = blockIdx.x;
    int tid = threadIdx.x;
    int c = tid * 8;
    if (b < P0_W) {                       // Wb row (m*2048+j)
        int m = b >> 11, j = b & 2047;
        const float* src = (c < INSZ) ? (Wih + ((size_t)m * G4H + j) * INSZ + c)
                                      : (Whh + ((size_t)m * G4H + j) * HID + (c - INSZ));
        u16* dst = Wb + (size_t)b * KIN + c;
        store_bf4(dst, *(const float4*)src);
        store_bf4(dst + 4, *(const float4*)(src + 4));
    } else if (b < P0_W + P0_L) {         // Wlin: 3 rows of 512 per block
        int row = (b - P0_W) * 3 + (c >> 9);
        int col = c & 511;
        if (row >= KCAT * CCH) return;
        const float* src = W_lin + (size_t)row * HID + col;
        u16* dst = Wlin + (size_t)row * HID + col;
        store_bf4(dst, *(const float4*)src);
        store_bf4(dst + 4, *(const float4*)(src + 4));
    } else {                              // build_perm (single block)
        __shared__ int cnt_ci[MCELL], cur_ci[MCELL];
        __shared__ int cnt_cat[KCAT], cur_cat[KCAT];
        if (tid < MCELL) cnt_ci[tid] = 0;
        if (tid < KCAT)  cnt_cat[tid] = 0;
        __syncthreads();
        for (int t = tid; t < NTOK; t += 192) {
            atomicAdd(&cnt_ci[ci[t]], 1);
            atomicAdd(&cnt_cat[cat[t]], 1);
        }
        __syncthreads();
        if (tid == 0) {
            int off = 0;
            for (int m = 0; m < MCELL; ++m) {
                int p = (cnt_ci[m] + 127) & ~127;
                meta[m] = p; meta[4 + m] = off; cur_ci[m] = off; off += p;
            }
            off = 0;
            for (int i = 0; i < 128; ++i) meta[136 + i] = -1;
            for (int k = 0; k < KCAT; ++k) {
                int p = (cnt_cat[k] + 63) & ~63;
                meta[8 + k] = p; meta[72 + k] = off; cur_cat[k] = off;
                for (int i = 0; i < p / 64; ++i) meta[136 + off / 64 + i] = k;
                off += p;
            }
        }
        __syncthreads();
        for (int i = tid; i < 4608; i += 192) perm_ci[i] = -1;
        for (int i = tid; i < 8192; i += 192) perm_cat[i] = -1;
        __syncthreads();
        for (int t = tid; t < NTOK; t += 192) {
            int s = atomicAdd(&cur_ci[ci[t]], 1);
            perm_ci[s] = t;
            int sc = atomicAdd(&cur_cat[cat[t]], 1);
            perm_cat[sc] = t;
        }
    }
}

// ---------------------------------------------------------------------------
// Dispatch 1: A_pack (ci-slot order bf16 [x|h]) + inv_ci.
// ---------------------------------------------------------------------------
__global__ __launch_bounds__(192) void pack_slots(
    const float* __restrict__ x, const float* __restrict__ h,
    const int* __restrict__ perm_ci,
    u16* __restrict__ A_pack, int* __restrict__ inv_ci)
{
    int b = blockIdx.x;
    int tid = threadIdx.x;
    int c = tid * 8;
    int t = perm_ci[b];
    if (tid == 0 && t >= 0) inv_ci[t] = b;
    u16* dst = A_pack + (size_t)b * KIN + c;
    if (t < 0) {
        *reinterpret_cast<int4*>(dst) = make_int4(0, 0, 0, 0);
        return;
    }
    const float* src = (c < INSZ) ? (x + (size_t)t * INSZ + c)
                                  : (h + (size_t)t * HID + (c - INSZ));
    store_bf4(dst, *(const float4*)src);
    store_bf4(dst + 4, *(const float4*)(src + 4));
}

// ---------------------------------------------------------------------------
// Dispatch 2: fused GEMMs, BK=64, barrier structure (R5-proven), plus:
//  - gates K-split x2 (seg in {0,1}, K-half 768 -> 12 iters) into gates0/1.
//  - XCD swizzle: 1D grid, id%64 = (m,ct) group -> same XCD (id%8) for all
//    row/seg tiles of one weight-column group; per-XCD Wb set ~3MB <= L2.
//  - ids [4608, 4736): log_odds 64x128 tiles, K=512 (8 iters), LUT tile->cat.
// LDS chunk-XOR swizzle keeps ds_read_b128 at 2-way aliasing (free, proven 0
// conflicts since R2).
// ---------------------------------------------------------------------------
__global__ __launch_bounds__(256, 4) void mega_gemm(
    const u16* __restrict__ A_pack,   // [4608][1536] ci-slot order
    const u16* __restrict__ Wb,       // [4][2048][1536]
    const u16* __restrict__ Wlin,     // [64][128][512]
    const float* __restrict__ et,     // [4096][512] f32
    const float* __restrict__ b_lin,  // [64,128]
    const int* __restrict__ meta,
    const int* __restrict__ perm_cat,
    u16* __restrict__ gates0,         // [4608][2048] bf16 partial (K 0..768)
    u16* __restrict__ gates1,         // [4608][2048] bf16 partial (K 768..1536)
    float* __restrict__ out)          // log_odds at out[0..N*128)
{
    __shared__ __align__(16) u16 As[8192];   // 16 KB
    __shared__ __align__(16) u16 Bs[8192];   // 16 KB
    __shared__ int sperm[64];

    int tid = threadIdx.x;
    int lane = tid & 63, wave = tid >> 6;
    int rb = tid >> 3;                        // staging row-within-32 (0..31)
    int kc = (tid & 7) ^ (rb & 7);            // swizzled source k-chunk
    int qd = lane >> 4, l15 = lane & 15;
    int rsw = l15 & 7;                        // frag-read row swizzle key

    int id = blockIdx.x;
    if (id < 4608) {
        // ---------------- gates GEMM (K-split) ----------------
        int g = id & 63;                      // (m,ct) group -> fixes XCD
        int r = id >> 6;                      // 0..71
        int m = g >> 4, ct = g & 15;
        int seg = r & 1, rt = r >> 1;         // rt 0..35
        int pcnt = meta[m];
        if (rt * 128 >= pcnt) return;
        int row0 = meta[4 + m] + rt * 128;
        int k0 = seg * KSEG;

        const u16* gA[4]; const u16* gB[4];
        u16* lA[4]; u16* lB[4];
        #pragma unroll
        for (int i = 0; i < 4; ++i) {
            gA[i] = A_pack + (size_t)(row0 + i * 32 + rb) * KIN + k0 + kc * 8;
            gB[i] = Wb + ((size_t)m * G4H + ct * 128 + i * 32 + rb) * KIN + k0 + kc * 8;
            lA[i] = As + (i * 256 + wave * 64) * 8;
            lB[i] = Bs + (i * 256 + wave * 64) * 8;
        }

        int wr = wave >> 1, wc = wave & 1;

        f32x4 acc[4][4];
        #pragma unroll
        for (int i = 0; i < 4; ++i)
            #pragma unroll
            for (int j = 0; j < 4; ++j)
                acc[i][j] = (f32x4){0.f, 0.f, 0.f, 0.f};

        for (int ks = 0; ks < KSEG / 64; ++ks) {
            #pragma unroll
            for (int i = 0; i < 4; ++i) { gl16(gA[i], lA[i]); gl16(gB[i], lB[i]); }
            #pragma unroll
            for (int i = 0; i < 4; ++i) { gA[i] += 64; gB[i] += 64; }
            __syncthreads();
            #pragma unroll
            for (int ks2 = 0; ks2 < 2; ++ks2) {
                bf16x8 fa[4], fb[4];
                #pragma unroll
                for (int ti = 0; ti < 4; ++ti) {
                    int row = wr * 64 + ti * 16 + l15;
                    int ch = (ks2 * 4 + qd) ^ rsw;
                    fa[ti] = *reinterpret_cast<const bf16x8*>(&As[row * 64 + ch * 8]);
                }
                #pragma unroll
                for (int tj = 0; tj < 4; ++tj) {
                    int row = wc * 64 + tj * 16 + l15;
                    int ch = (ks2 * 4 + qd) ^ rsw;
                    fb[tj] = *reinterpret_cast<const bf16x8*>(&Bs[row * 64 + ch * 8]);
                }
                #pragma unroll
                for (int ti = 0; ti < 4; ++ti)
                    #pragma unroll
                    for (int tj = 0; tj < 4; ++tj)
                        acc[ti][tj] = __builtin_amdgcn_mfma_f32_16x16x32_bf16(fa[ti], fb[tj], acc[ti][tj], 0, 0, 0);
            }
            __syncthreads();
        }

        u16* gout = seg ? gates1 : gates0;
        #pragma unroll
        for (int ti = 0; ti < 4; ++ti) {
            #pragma unroll
            for (int tj = 0; tj < 4; ++tj) {
                int gcol = ct * 128 + wc * 64 + tj * 16 + l15;
                #pragma unroll
                for (int rr = 0; rr < 4; ++rr) {
                    int grow = row0 + wr * 64 + ti * 16 + qd * 4 + rr;
                    gout[(size_t)grow * G4H + gcol] = f2bf(acc[ti][tj][rr]);
                }
            }
        }
    } else {
        // ---------------- log_odds GEMM (64 x 128, K=512) ----------------
        int rtl = id - 4608;                  // 0..127 global slot tile
        int k = meta[136 + rtl];
        if (k < 0) return;
        int r0 = rtl * 64;

        if (tid < 64) sperm[tid] = perm_cat[r0 + tid];
        __syncthreads();

        // B = Wlin[k] (128 x 64/iter) via gl16 into As
        const u16* gW[4]; u16* lW[4];
        #pragma unroll
        for (int i = 0; i < 4; ++i) {
            gW[i] = Wlin + ((size_t)k * CCH + i * 32 + rb) * HID + kc * 8;
            lW[i] = As + (i * 256 + wave * 64) * 8;
        }
        // A = et rows gathered, f32->bf16 VALU staging into Bs (64 x 64/iter)
        int ar = tid >> 2;                    // 0..63
        int acp = tid & 3;                    // 2 chunks each
        int at = sperm[ar];
        const float* asrc = (at >= 0) ? (et + (size_t)at * HID) : nullptr;

        f32x4 acc[4][2];
        #pragma unroll
        for (int i = 0; i < 4; ++i) {
            acc[i][0] = (f32x4){0.f, 0.f, 0.f, 0.f};
            acc[i][1] = (f32x4){0.f, 0.f, 0.f, 0.f};
        }

        for (int kk = 0; kk < HID; kk += 64) {
            #pragma unroll
            for (int i = 0; i < 4; ++i) { gl16(gW[i], lW[i]); gW[i] += 64; }
            #pragma unroll
            for (int j = 0; j < 2; ++j) {
                int dch = acp * 2 + j;
                int sch = dch ^ (ar & 7);
                u16* dst = &Bs[ar * 64 + dch * 8];
                if (asrc) {
                    const float* s = asrc + kk + sch * 8;
                    store_bf4(dst,     *(const float4*)s);
                    store_bf4(dst + 4, *(const float4*)(s + 4));
                } else {
                    *reinterpret_cast<int4*>(dst) = make_int4(0, 0, 0, 0);
                }
            }
            __syncthreads();
            #pragma unroll
            for (int ks2 = 0; ks2 < 2; ++ks2) {
                bf16x8 fa[4], fb[2];
                #pragma unroll
                for (int ti = 0; ti < 4; ++ti) {
                    int row = ti * 16 + l15;
                    int ch = (ks2 * 4 + qd) ^ rsw;
                    fa[ti] = *reinterpret_cast<const bf16x8*>(&Bs[row * 64 + ch * 8]);
                }
                #pragma unroll
                for (int tj = 0; tj < 2; ++tj) {
                    int row = wave * 32 + tj * 16 + l15;
                    int ch = (ks2 * 4 + qd) ^ rsw;
                    fb[tj] = *reinterpret_cast<const bf16x8*>(&As[row * 64 + ch * 8]);
                }
                #pragma unroll
                for (int ti = 0; ti < 4; ++ti)
                    #pragma unroll
                    for (int tj = 0; tj < 2; ++tj)
                        acc[ti][tj] = __builtin_amdgcn_mfma_f32_16x16x32_bf16(fa[ti], fb[tj], acc[ti][tj], 0, 0, 0);
            }
            __syncthreads();
        }

        #pragma unroll
        for (int ti = 0; ti < 4; ++ti) {
            #pragma unroll
            for (int tj = 0; tj < 2; ++tj) {
                int n = wave * 32 + tj * 16 + l15;
                float bias = b_lin[k * CCH + n];
                #pragma unroll
                for (int rr = 0; rr < 4; ++rr) {
                    int row = ti * 16 + qd * 4 + rr;
                    int t = sperm[row];
                    if (t >= 0)
                        out[(size_t)t * CCH + n] = acc[ti][tj][rr] + bias;
                }
            }
        }
    }
}

// ---------------------------------------------------------------------------
// Dispatch 3: LSTM pointwise epilogue; sums the two K-split partials.
// ---------------------------------------------------------------------------
__global__ __launch_bounds__(256) void lstm_epilogue(
    const u16* __restrict__ gates0, const u16* __restrict__ gates1,
    const int* __restrict__ meta,
    const int* __restrict__ inv_ci,
    const float* __restrict__ c,
    const float* __restrict__ b_ih,   // [4,2048]
    const float* __restrict__ b_hh,   // [4,2048]
    float* __restrict__ out)
{
    int idx = blockIdx.x * 256 + threadIdx.x;   // [0, N*512)
    int t = idx >> 9;
    int hh = idx & 511;
    int s = inv_ci[t];
    int m = (s >= meta[5]) + (s >= meta[6]) + (s >= meta[7]);

    const u16* g0 = gates0 + (size_t)s * G4H;
    const u16* g1 = gates1 + (size_t)s * G4H;
    const float* bi = b_ih + (size_t)m * G4H;
    const float* bh = b_hh + (size_t)m * G4H;
    float gi = bf2f(g0[hh])        + bf2f(g1[hh])        + bi[hh]        + bh[hh];
    float gf = bf2f(g0[512 + hh])  + bf2f(g1[512 + hh])  + bi[512 + hh]  + bh[512 + hh];
    float gg = bf2f(g0[1024 + hh]) + bf2f(g1[1024 + hh]) + bi[1024 + hh] + bh[1024 + hh];
    float go = bf2f(g0[1536 + hh]) + bf2f(g1[1536 + hh]) + bi[1536 + hh] + bh[1536 + hh];

    float si = 1.f / (1.f + __expf(-gi));
    float sf = 1.f / (1.f + __expf(-gf));
    float so = 1.f / (1.f + __expf(-go));
    float ct = c[(size_t)t * HID + hh];
    float c2 = sf * ct + si * tanhf(gg);
    float h2 = so * tanhf(c2);

    const size_t o_h2 = (size_t)NTOK * CCH;
    const size_t o_c2 = o_h2 + (size_t)NTOK * HID;
    out[o_h2 + (size_t)t * HID + hh] = h2;
    out[o_c2 + (size_t)t * HID + hh] = c2;
}

// ---------------------------------------------------------------------------
extern "C" void kernel_launch(void* const* d_in, const int* in_sizes, int n_in,
                              void* d_out, int out_size, void* d_ws, size_t ws_size,
                              hipStream_t stream) {
    const float* et    = (const float*)d_in[0];
    const float* x     = (const float*)d_in[1];
    const float* h     = (const float*)d_in[2];
    const float* c     = (const float*)d_in[3];
    const int*   cat   = (const int*)d_in[4];
    const int*   ci    = (const int*)d_in[5];
    const float* W_lin = (const float*)d_in[6];
    const float* b_lin = (const float*)d_in[7];
    const float* W_ih  = (const float*)d_in[8];
    const float* W_hh  = (const float*)d_in[9];
    const float* b_ih  = (const float*)d_in[10];
    const float* b_hh  = (const float*)d_in[11];
    float* out = (float*)d_out;

    char* ws = (char*)d_ws;
    int* meta     = (int*)ws;                         // 512 ints (incl. LUT)
    int* perm_ci  = (int*)(ws + 2048);                // -> 20480
    int* perm_cat = (int*)(ws + 20480);               // -> 53248
    int* inv_ci   = (int*)(ws + 53248);               // -> 69632
    u16* A_pack   = (u16*)(ws + 69632);               // -> 14225408
    u16* Wb       = (u16*)(ws + 14225408);            // -> 39391232
    u16* Wlin     = (u16*)(ws + 39391232);            // -> 47779840
    u16* gates0   = (u16*)(ws + 47779840);            // -> 66654208
    u16* gates1   = (u16*)(ws + 66654208);            // -> 85528576 (~85.5 MB)

    pack_all<<<P0_W + P0_L + 1, 192, 0, stream>>>(W_ih, W_hh, W_lin, ci, cat,
                                                  Wb, Wlin, meta, perm_ci, perm_cat);

    pack_slots<<<4608, 192, 0, stream>>>(x, h, perm_ci, A_pack, inv_ci);

    mega_gemm<<<4608 + 128, 256, 0, stream>>>(A_pack, Wb, Wlin, et, b_lin, meta,
                                              perm_cat, gates0, gates1, out);

    lstm_epilogue<<<(NTOK * HID) / 256, 256, 0, stream>>>(gates0, gates1, meta,
                                                          inv_ci, c, b_ih, b_hh, out);
}

// Round 8
// 236.557 us; speedup vs baseline: 1.5127x; 1.0941x over previous
//
#include <hip/hip_runtime.h>
#include <hip/hip_bf16.h>
#include <stdint.h>

// Problem constants (fixed by the reference)
#define NTOK 4096
#define HID  512
#define INSZ 1024   // E + H
#define KIN  1536   // INSZ + HID (fused LSTM input: x | h)
#define KSEG 768    // K-split half
#define KCAT 64
#define CCH  128
#define MCELL 4
#define G4H  2048   // 4*H

typedef unsigned short u16;
typedef __bf16 bf16x8 __attribute__((ext_vector_type(8)));
typedef float  f32x4  __attribute__((ext_vector_type(4)));

__device__ __forceinline__ u16 f2bf(float f) {
    unsigned u = __float_as_uint(f);
    u += 0x7fffu + ((u >> 16) & 1u);   // RTNE
    return (u16)(u >> 16);
}
__device__ __forceinline__ float bf2f(u16 v) {
    return __uint_as_float(((unsigned)v) << 16);
}
__device__ __forceinline__ void store_bf8(u16* p, float4 a, float4 b) {
    ushort4 r0, r1;
    r0.x = f2bf(a.x); r0.y = f2bf(a.y); r0.z = f2bf(a.z); r0.w = f2bf(a.w);
    r1.x = f2bf(b.x); r1.y = f2bf(b.y); r1.z = f2bf(b.z); r1.w = f2bf(b.w);
    *reinterpret_cast<ushort4*>(p) = r0;
    *reinterpret_cast<ushort4*>(p + 4) = r1;
}
__device__ __forceinline__ void gl16(const u16* g, u16* l) {
    __builtin_amdgcn_global_load_lds((const __attribute__((address_space(1))) void*)g,
                                     (__attribute__((address_space(3))) void*)l, 16, 0, 0);
}

// meta layout (ints): [0..3] ci padded cnt, [4..7] ci padded off,
// [8..71] cat padded cnt, [72..135] cat padded off, [136..263] tile->cat LUT
// ---------------------------------------------------------------------------
// Dispatch 0: build_perm — ci/cat bucketing, inv_ci, tile->cat LUT. 1 block.
// ---------------------------------------------------------------------------
__global__ __launch_bounds__(1024) void build_perm(
    const int* __restrict__ ci, const int* __restrict__ cat,
    int* __restrict__ meta, int* __restrict__ perm_ci,
    int* __restrict__ inv_ci, int* __restrict__ perm_cat)
{
    __shared__ int cnt_ci[MCELL], cur_ci[MCELL];
    __shared__ int cnt_cat[KCAT], cur_cat[KCAT];
    int tid = threadIdx.x;
    if (tid < MCELL) cnt_ci[tid] = 0;
    if (tid < KCAT)  cnt_cat[tid] = 0;
    __syncthreads();
    for (int t = tid; t < NTOK; t += 1024) {
        atomicAdd(&cnt_ci[ci[t]], 1);
        atomicAdd(&cnt_cat[cat[t]], 1);
    }
    __syncthreads();
    if (tid == 0) {
        int off = 0;
        for (int m = 0; m < MCELL; ++m) {
            int p = (cnt_ci[m] + 127) & ~127;
            meta[m] = p; meta[4 + m] = off; cur_ci[m] = off; off += p;
        }
        off = 0;
        for (int i = 0; i < 128; ++i) meta[136 + i] = -1;
        for (int k = 0; k < KCAT; ++k) {
            int p = (cnt_cat[k] + 63) & ~63;
            meta[8 + k] = p; meta[72 + k] = off; cur_cat[k] = off;
            for (int i = 0; i < p / 64; ++i) meta[136 + off / 64 + i] = k;
            off += p;
        }
    }
    __syncthreads();
    for (int i = tid; i < 4608; i += 1024) perm_ci[i] = -1;
    for (int i = tid; i < 8192; i += 1024) perm_cat[i] = -1;
    __syncthreads();
    for (int t = tid; t < NTOK; t += 1024) {
        int s = atomicAdd(&cur_ci[ci[t]], 1);
        perm_ci[s] = t;
        inv_ci[t] = s;
        int sc = atomicAdd(&cur_cat[cat[t]], 1);
        perm_cat[sc] = t;
    }
}

// ---------------------------------------------------------------------------
// Dispatch 1: fat grid-stride pack. One 16B-dst chunk per work item:
//   [0, CH_W)            : Wb   (W_ih|W_hh -> bf16), 8192 rows x 192 chunks
//   [CH_W, +CH_L)        : Wlin (bf16), 8192 rows x 64 chunks
//   [.., +CH_A)          : A_pack ci-slot gather [x|h], 4608 rows x 192 chunks
// 256-thread blocks, ~6 iterations each, independent load->cvt->store streams.
// ---------------------------------------------------------------------------
#define CH_W  (8192 * 192)
#define CH_L  (8192 * 64)
#define CH_A  (4608 * 192)
#define CH_TOT (CH_W + CH_L + CH_A)
#define PK_BLOCKS 2048

__global__ __launch_bounds__(256) void fat_pack(
    const float* __restrict__ x, const float* __restrict__ h,
    const float* __restrict__ Wih, const float* __restrict__ Whh,
    const float* __restrict__ W_lin,
    const int* __restrict__ perm_ci,
    u16* __restrict__ A_pack, u16* __restrict__ Wb, u16* __restrict__ Wlin)
{
    for (int i = blockIdx.x * 256 + threadIdx.x; i < CH_TOT; i += PK_BLOCKS * 256) {
        if (i < CH_W) {
            int row = i / 192, cc = i - row * 192;
            int m = row >> 11, j = row & 2047;
            int c = cc * 8;
            const float* src = (c < INSZ) ? (Wih + ((size_t)m * G4H + j) * INSZ + c)
                                          : (Whh + ((size_t)m * G4H + j) * HID + (c - INSZ));
            store_bf8(Wb + (size_t)row * KIN + c,
                      *(const float4*)src, *(const float4*)(src + 4));
        } else if (i < CH_W + CH_L) {
            int i2 = i - CH_W;
            int row = i2 >> 6, cc = i2 & 63;
            const float* src = W_lin + (size_t)row * HID + cc * 8;
            store_bf8(Wlin + (size_t)row * HID + cc * 8,
                      *(const float4*)src, *(const float4*)(src + 4));
        } else {
            int i3 = i - (CH_W + CH_L);
            int row = i3 / 192, cc = i3 - row * 192;
            int c = cc * 8;
            u16* dst = A_pack + (size_t)row * KIN + c;
            int t = perm_ci[row];
            if (t < 0) {
                *reinterpret_cast<int4*>(dst) = make_int4(0, 0, 0, 0);
            } else {
                const float* src = (c < INSZ) ? (x + (size_t)t * INSZ + c)
                                              : (h + (size_t)t * HID + (c - INSZ));
                store_bf8(dst, *(const float4*)src, *(const float4*)(src + 4));
            }
        }
    }
}

// ---------------------------------------------------------------------------
// Dispatch 2: fused GEMMs, BK=64, barrier structure + K-split x2 + XCD
// swizzle (R7-proven, unchanged).
// ---------------------------------------------------------------------------
__global__ __launch_bounds__(256, 4) void mega_gemm(
    const u16* __restrict__ A_pack,   // [4608][1536] ci-slot order
    const u16* __restrict__ Wb,       // [4][2048][1536]
    const u16* __restrict__ Wlin,     // [64][128][512]
    const float* __restrict__ et,     // [4096][512] f32
    const float* __restrict__ b_lin,  // [64,128]
    const int* __restrict__ meta,
    const int* __restrict__ perm_cat,
    u16* __restrict__ gates0,         // [4608][2048] bf16 partial (K 0..768)
    u16* __restrict__ gates1,         // [4608][2048] bf16 partial (K 768..1536)
    float* __restrict__ out)          // log_odds at out[0..N*128)
{
    __shared__ __align__(16) u16 As[8192];   // 16 KB
    __shared__ __align__(16) u16 Bs[8192];   // 16 KB
    __shared__ int sperm[64];

    int tid = threadIdx.x;
    int lane = tid & 63, wave = tid >> 6;
    int rb = tid >> 3;                        // staging row-within-32 (0..31)
    int kc = (tid & 7) ^ (rb & 7);            // swizzled source k-chunk
    int qd = lane >> 4, l15 = lane & 15;
    int rsw = l15 & 7;                        // frag-read row swizzle key

    int id = blockIdx.x;
    if (id < 4608) {
        // ---------------- gates GEMM (K-split) ----------------
        int g = id & 63;                      // (m,ct) group -> fixes XCD
        int r = id >> 6;                      // 0..71
        int m = g >> 4, ct = g & 15;
        int seg = r & 1, rt = r >> 1;         // rt 0..35
        int pcnt = meta[m];
        if (rt * 128 >= pcnt) return;
        int row0 = meta[4 + m] + rt * 128;
        int k0 = seg * KSEG;

        const u16* gA[4]; const u16* gB[4];
        u16* lA[4]; u16* lB[4];
        #pragma unroll
        for (int i = 0; i < 4; ++i) {
            gA[i] = A_pack + (size_t)(row0 + i * 32 + rb) * KIN + k0 + kc * 8;
            gB[i] = Wb + ((size_t)m * G4H + ct * 128 + i * 32 + rb) * KIN + k0 + kc * 8;
            lA[i] = As + (i * 256 + wave * 64) * 8;
            lB[i] = Bs + (i * 256 + wave * 64) * 8;
        }

        int wr = wave >> 1, wc = wave & 1;

        f32x4 acc[4][4];
        #pragma unroll
        for (int i = 0; i < 4; ++i)
            #pragma unroll
            for (int j = 0; j < 4; ++j)
                acc[i][j] = (f32x4){0.f, 0.f, 0.f, 0.f};

        for (int ks = 0; ks < KSEG / 64; ++ks) {
            #pragma unroll
            for (int i = 0; i < 4; ++i) { gl16(gA[i], lA[i]); gl16(gB[i], lB[i]); }
            #pragma unroll
            for (int i = 0; i < 4; ++i) { gA[i] += 64; gB[i] += 64; }
            __syncthreads();
            #pragma unroll
            for (int ks2 = 0; ks2 < 2; ++ks2) {
                bf16x8 fa[4], fb[4];
                #pragma unroll
                for (int ti = 0; ti < 4; ++ti) {
                    int row = wr * 64 + ti * 16 + l15;
                    int ch = (ks2 * 4 + qd) ^ rsw;
                    fa[ti] = *reinterpret_cast<const bf16x8*>(&As[row * 64 + ch * 8]);
                }
                #pragma unroll
                for (int tj = 0; tj < 4; ++tj) {
                    int row = wc * 64 + tj * 16 + l15;
                    int ch = (ks2 * 4 + qd) ^ rsw;
                    fb[tj] = *reinterpret_cast<const bf16x8*>(&Bs[row * 64 + ch * 8]);
                }
                #pragma unroll
                for (int ti = 0; ti < 4; ++ti)
                    #pragma unroll
                    for (int tj = 0; tj < 4; ++tj)
                        acc[ti][tj] = __builtin_amdgcn_mfma_f32_16x16x32_bf16(fa[ti], fb[tj], acc[ti][tj], 0, 0, 0);
            }
            __syncthreads();
        }

        u16* gout = seg ? gates1 : gates0;
        #pragma unroll
        for (int ti = 0; ti < 4; ++ti) {
            #pragma unroll
            for (int tj = 0; tj < 4; ++tj) {
                int gcol = ct * 128 + wc * 64 + tj * 16 + l15;
                #pragma unroll
                for (int rr = 0; rr < 4; ++rr) {
                    int grow = row0 + wr * 64 + ti * 16 + qd * 4 + rr;
                    gout[(size_t)grow * G4H + gcol] = f2bf(acc[ti][tj][rr]);
                }
            }
        }
    } else {
        // ---------------- log_odds GEMM (64 x 128, K=512) ----------------
        int rtl = id - 4608;                  // 0..127 global slot tile
        int k = meta[136 + rtl];
        if (k < 0) return;
        int r0 = rtl * 64;

        if (tid < 64) sperm[tid] = perm_cat[r0 + tid];
        __syncthreads();

        // B = Wlin[k] (128 x 64/iter) via gl16 into As
        const u16* gW[4]; u16* lW[4];
        #pragma unroll
        for (int i = 0; i < 4; ++i) {
            gW[i] = Wlin + ((size_t)k * CCH + i * 32 + rb) * HID + kc * 8;
            lW[i] = As + (i * 256 + wave * 64) * 8;
        }
        // A = et rows gathered, f32->bf16 VALU staging into Bs (64 x 64/iter)
        int ar = tid >> 2;                    // 0..63
        int acp = tid & 3;                    // 2 chunks each
        int at = sperm[ar];
        const float* asrc = (at >= 0) ? (et + (size_t)at * HID) : nullptr;

        f32x4 acc[4][2];
        #pragma unroll
        for (int i = 0; i < 4; ++i) {
            acc[i][0] = (f32x4){0.f, 0.f, 0.f, 0.f};
            acc[i][1] = (f32x4){0.f, 0.f, 0.f, 0.f};
        }

        for (int kk = 0; kk < HID; kk += 64) {
            #pragma unroll
            for (int i = 0; i < 4; ++i) { gl16(gW[i], lW[i]); gW[i] += 64; }
            #pragma unroll
            for (int j = 0; j < 2; ++j) {
                int dch = acp * 2 + j;
                int sch = dch ^ (ar & 7);
                u16* dst = &Bs[ar * 64 + dch * 8];
                if (asrc) {
                    const float* s = asrc + kk + sch * 8;
                    store_bf8(dst, *(const float4*)s, *(const float4*)(s + 4));
                } else {
                    *reinterpret_cast<int4*>(dst) = make_int4(0, 0, 0, 0);
                }
            }
            __syncthreads();
            #pragma unroll
            for (int ks2 = 0; ks2 < 2; ++ks2) {
                bf16x8 fa[4], fb[2];
                #pragma unroll
                for (int ti = 0; ti < 4; ++ti) {
                    int row = ti * 16 + l15;
                    int ch = (ks2 * 4 + qd) ^ rsw;
                    fa[ti] = *reinterpret_cast<const bf16x8*>(&Bs[row * 64 + ch * 8]);
                }
                #pragma unroll
                for (int tj = 0; tj < 2; ++tj) {
                    int row = wave * 32 + tj * 16 + l15;
                    int ch = (ks2 * 4 + qd) ^ rsw;
                    fb[tj] = *reinterpret_cast<const bf16x8*>(&As[row * 64 + ch * 8]);
                }
                #pragma unroll
                for (int ti = 0; ti < 4; ++ti)
                    #pragma unroll
                    for (int tj = 0; tj < 2; ++tj)
                        acc[ti][tj] = __builtin_amdgcn_mfma_f32_16x16x32_bf16(fa[ti], fb[tj], acc[ti][tj], 0, 0, 0);
            }
            __syncthreads();
        }

        #pragma unroll
        for (int ti = 0; ti < 4; ++ti) {
            #pragma unroll
            for (int tj = 0; tj < 2; ++tj) {
                int n = wave * 32 + tj * 16 + l15;
                float bias = b_lin[k * CCH + n];
                #pragma unroll
                for (int rr = 0; rr < 4; ++rr) {
                    int row = ti * 16 + qd * 4 + rr;
                    int t = sperm[row];
                    if (t >= 0)
                        out[(size_t)t * CCH + n] = acc[ti][tj][rr] + bias;
                }
            }
        }
    }
}

// ---------------------------------------------------------------------------
// Dispatch 3: LSTM pointwise epilogue; sums the two K-split partials.
// ---------------------------------------------------------------------------
__global__ __launch_bounds__(256) void lstm_epilogue(
    const u16* __restrict__ gates0, const u16* __restrict__ gates1,
    const int* __restrict__ meta,
    const int* __restrict__ inv_ci,
    const float* __restrict__ c,
    const float* __restrict__ b_ih,   // [4,2048]
    const float* __restrict__ b_hh,   // [4,2048]
    float* __restrict__ out)
{
    int idx = blockIdx.x * 256 + threadIdx.x;   // [0, N*512)
    int t = idx >> 9;
    int hh = idx & 511;
    int s = inv_ci[t];
    int m = (s >= meta[5]) + (s >= meta[6]) + (s >= meta[7]);

    const u16* g0 = gates0 + (size_t)s * G4H;
    const u16* g1 = gates1 + (size_t)s * G4H;
    const float* bi = b_ih + (size_t)m * G4H;
    const float* bh = b_hh + (size_t)m * G4H;
    float gi = bf2f(g0[hh])        + bf2f(g1[hh])        + bi[hh]        + bh[hh];
    float gf = bf2f(g0[512 + hh])  + bf2f(g1[512 + hh])  + bi[512 + hh]  + bh[512 + hh];
    float gg = bf2f(g0[1024 + hh]) + bf2f(g1[1024 + hh]) + bi[1024 + hh] + bh[1024 + hh];
    float go = bf2f(g0[1536 + hh]) + bf2f(g1[1536 + hh]) + bi[1536 + hh] + bh[1536 + hh];

    float si = 1.f / (1.f + __expf(-gi));
    float sf = 1.f / (1.f + __expf(-gf));
    float so = 1.f / (1.f + __expf(-go));
    float ct = c[(size_t)t * HID + hh];
    float c2 = sf * ct + si * tanhf(gg);
    float h2 = so * tanhf(c2);

    const size_t o_h2 = (size_t)NTOK * CCH;
    const size_t o_c2 = o_h2 + (size_t)NTOK * HID;
    out[o_h2 + (size_t)t * HID + hh] = h2;
    out[o_c2 + (size_t)t * HID + hh] = c2;
}

// ---------------------------------------------------------------------------
extern "C" void kernel_launch(void* const* d_in, const int* in_sizes, int n_in,
                              void* d_out, int out_size, void* d_ws, size_t ws_size,
                              hipStream_t stream) {
    const float* et    = (const float*)d_in[0];
    const float* x     = (const float*)d_in[1];
    const float* h     = (const float*)d_in[2];
    const float* c     = (const float*)d_in[3];
    const int*   cat   = (const int*)d_in[4];
    const int*   ci    = (const int*)d_in[5];
    const float* W_lin = (const float*)d_in[6];
    const float* b_lin = (const float*)d_in[7];
    const float* W_ih  = (const float*)d_in[8];
    const float* W_hh  = (const float*)d_in[9];
    const float* b_ih  = (const float*)d_in[10];
    const float* b_hh  = (const float*)d_in[11];
    float* out = (float*)d_out;

    char* ws = (char*)d_ws;
    int* meta     = (int*)ws;                         // 512 ints (incl. LUT)
    int* perm_ci  = (int*)(ws + 2048);                // -> 20480
    int* perm_cat = (int*)(ws + 20480);               // -> 53248
    int* inv_ci   = (int*)(ws + 53248);               // -> 69632
    u16* A_pack   = (u16*)(ws + 69632);               // -> 14225408
    u16* Wb       = (u16*)(ws + 14225408);            // -> 39391232
    u16* Wlin     = (u16*)(ws + 39391232);            // -> 47779840
    u16* gates0   = (u16*)(ws + 47779840);            // -> 66654208
    u16* gates1   = (u16*)(ws + 66654208);            // -> 85528576 (~85.5 MB)

    build_perm<<<1, 1024, 0, stream>>>(ci, cat, meta, perm_ci, inv_ci, perm_cat);

    fat_pack<<<PK_BLOCKS, 256, 0, stream>>>(x, h, W_ih, W_hh, W_lin, perm_ci,
                                            A_pack, Wb, Wlin);

    mega_gemm<<<4608 + 128, 256, 0, stream>>>(A_pack, Wb, Wlin, et, b_lin, meta,
                                              perm_cat, gates0, gates1, out);

    lstm_epilogue<<<(NTOK * HID) / 256, 256, 0, stream>>>(gates0, gates1, meta,
                                                          inv_ci, c, b_ih, b_hh, out);
}

// Round 9
// 236.064 us; speedup vs baseline: 1.5158x; 1.0021x over previous
//
#include <hip/hip_runtime.h>
#include <hip/hip_bf16.h>
#include <stdint.h>

// Problem constants (fixed by the reference)
#define NTOK 4096
#define HID  512
#define INSZ 1024   // E + H
#define KIN  1536   // INSZ + HID (fused LSTM input: x | h)
#define KSEG 768    // K-split half
#define KCAT 64
#define CCH  128
#define MCELL 4
#define G4H  2048   // 4*H
#define AROWS 5120  // A_pack rows (4 buckets padded to 256)

typedef unsigned short u16;
typedef __bf16 bf16x8 __attribute__((ext_vector_type(8)));
typedef float  f32x4  __attribute__((ext_vector_type(4)));

__device__ __forceinline__ u16 f2bf(float f) {
    unsigned u = __float_as_uint(f);
    u += 0x7fffu + ((u >> 16) & 1u);   // RTNE
    return (u16)(u >> 16);
}
__device__ __forceinline__ float bf2f(u16 v) {
    return __uint_as_float(((unsigned)v) << 16);
}
__device__ __forceinline__ void store_bf8(u16* p, float4 a, float4 b) {
    ushort4 r0, r1;
    r0.x = f2bf(a.x); r0.y = f2bf(a.y); r0.z = f2bf(a.z); r0.w = f2bf(a.w);
    r1.x = f2bf(b.x); r1.y = f2bf(b.y); r1.z = f2bf(b.z); r1.w = f2bf(b.w);
    *reinterpret_cast<ushort4*>(p) = r0;
    *reinterpret_cast<ushort4*>(p + 4) = r1;
}
__device__ __forceinline__ void gl16(const u16* g, u16* l) {
    __builtin_amdgcn_global_load_lds((const __attribute__((address_space(1))) void*)g,
                                     (__attribute__((address_space(3))) void*)l, 16, 0, 0);
}

// meta layout (ints): [0..3] ci padded cnt, [4..7] ci padded off,
// [8..71] cat padded cnt, [72..135] cat padded off, [136..263] tile->cat LUT
// ---------------------------------------------------------------------------
// Dispatch 0: build_perm — ci buckets pad 256, cat buckets pad 64. 1 block.
// ---------------------------------------------------------------------------
__global__ __launch_bounds__(1024) void build_perm(
    const int* __restrict__ ci, const int* __restrict__ cat,
    int* __restrict__ meta, int* __restrict__ perm_ci,
    int* __restrict__ inv_ci, int* __restrict__ perm_cat)
{
    __shared__ int cnt_ci[MCELL], cur_ci[MCELL];
    __shared__ int cnt_cat[KCAT], cur_cat[KCAT];
    int tid = threadIdx.x;
    if (tid < MCELL) cnt_ci[tid] = 0;
    if (tid < KCAT)  cnt_cat[tid] = 0;
    __syncthreads();
    for (int t = tid; t < NTOK; t += 1024) {
        atomicAdd(&cnt_ci[ci[t]], 1);
        atomicAdd(&cnt_cat[cat[t]], 1);
    }
    __syncthreads();
    if (tid == 0) {
        int off = 0;
        for (int m = 0; m < MCELL; ++m) {
            int p = (cnt_ci[m] + 255) & ~255;
            meta[m] = p; meta[4 + m] = off; cur_ci[m] = off; off += p;
        }
        off = 0;
        for (int i = 0; i < 128; ++i) meta[136 + i] = -1;
        for (int k = 0; k < KCAT; ++k) {
            int p = (cnt_cat[k] + 63) & ~63;
            meta[8 + k] = p; meta[72 + k] = off; cur_cat[k] = off;
            for (int i = 0; i < p / 64; ++i) meta[136 + off / 64 + i] = k;
            off += p;
        }
    }
    __syncthreads();
    for (int i = tid; i < AROWS; i += 1024) perm_ci[i] = -1;
    for (int i = tid; i < 8192; i += 1024) perm_cat[i] = -1;
    __syncthreads();
    for (int t = tid; t < NTOK; t += 1024) {
        int s = atomicAdd(&cur_ci[ci[t]], 1);
        perm_ci[s] = t;
        inv_ci[t] = s;
        int sc = atomicAdd(&cur_cat[cat[t]], 1);
        perm_cat[sc] = t;
    }
}

// ---------------------------------------------------------------------------
// Dispatch 1: fat grid-stride pack (R8-proven).
// ---------------------------------------------------------------------------
#define CH_W  (8192 * 192)
#define CH_L  (8192 * 64)
#define CH_A  (AROWS * 192)
#define CH_TOT (CH_W + CH_L + CH_A)
#define PK_BLOCKS 2048

__global__ __launch_bounds__(256) void fat_pack(
    const float* __restrict__ x, const float* __restrict__ h,
    const float* __restrict__ Wih, const float* __restrict__ Whh,
    const float* __restrict__ W_lin,
    const int* __restrict__ perm_ci,
    u16* __restrict__ A_pack, u16* __restrict__ Wb, u16* __restrict__ Wlin)
{
    for (int i = blockIdx.x * 256 + threadIdx.x; i < CH_TOT; i += PK_BLOCKS * 256) {
        if (i < CH_W) {
            int row = i / 192, cc = i - row * 192;
            int m = row >> 11, j = row & 2047;
            int c = cc * 8;
            const float* src = (c < INSZ) ? (Wih + ((size_t)m * G4H + j) * INSZ + c)
                                          : (Whh + ((size_t)m * G4H + j) * HID + (c - INSZ));
            store_bf8(Wb + (size_t)row * KIN + c,
                      *(const float4*)src, *(const float4*)(src + 4));
        } else if (i < CH_W + CH_L) {
            int i2 = i - CH_W;
            int row = i2 >> 6, cc = i2 & 63;
            const float* src = W_lin + (size_t)row * HID + cc * 8;
            store_bf8(Wlin + (size_t)row * HID + cc * 8,
                      *(const float4*)src, *(const float4*)(src + 4));
        } else {
            int i3 = i - (CH_W + CH_L);
            int row = i3 / 192, cc = i3 - row * 192;
            int c = cc * 8;
            u16* dst = A_pack + (size_t)row * KIN + c;
            int t = perm_ci[row];
            if (t < 0) {
                *reinterpret_cast<int4*>(dst) = make_int4(0, 0, 0, 0);
            } else {
                const float* src = (c < INSZ) ? (x + (size_t)t * INSZ + c)
                                              : (h + (size_t)t * HID + (c - INSZ));
                store_bf8(dst, *(const float4*)src, *(const float4*)(src + 4));
            }
        }
    }
}

// ---------------------------------------------------------------------------
// Dispatch 2: fused GEMMs.
//  gates ids [0,1280): 256x128 block tile, 4 waves of 128x64 (8x4 frags)
//    -> FLOP per LDS-byte 42.7 (was 32 at 4x4); K-split x2; XCD swizzle.
//  logodds ids [1280,1408): 64x128 tiles, K=512 (R8-proven, unchanged).
// LDS chunk-XOR swizzle: LDS row r chunk c holds global k-chunk c^(r&7);
// frag reads land >=2-way bank aliasing (free, 0-conflict proven since R2).
// ---------------------------------------------------------------------------
__global__ __launch_bounds__(256, 2) void mega_gemm(
    const u16* __restrict__ A_pack,   // [5120][1536] ci-slot order
    const u16* __restrict__ Wb,       // [4][2048][1536]
    const u16* __restrict__ Wlin,     // [64][128][512]
    const float* __restrict__ et,     // [4096][512] f32
    const float* __restrict__ b_lin,  // [64,128]
    const int* __restrict__ meta,
    const int* __restrict__ perm_cat,
    u16* __restrict__ gates0,         // [5120][2048] bf16 partial (K 0..768)
    u16* __restrict__ gates1,         // [5120][2048] bf16 partial (K 768..1536)
    float* __restrict__ out)          // log_odds at out[0..N*128)
{
    __shared__ __align__(16) u16 As[16384];  // 32 KB (256 rows x 8 chunks)
    __shared__ __align__(16) u16 Bs[8192];   // 16 KB (128 rows x 8 chunks)
    __shared__ int sperm[64];

    int tid = threadIdx.x;
    int lane = tid & 63, wave = tid >> 6;
    int qd = lane >> 4, l15 = lane & 15;
    int rsw = l15 & 7;                        // frag-read chunk swizzle key

    int id = blockIdx.x;
    if (id < 1280) {
        // ---------------- gates GEMM (256x128, K-split) ----------------
        int g = id & 63;                      // (m,ct) group -> fixes XCD
        int r = id >> 6;                      // 0..19
        int m = g >> 4, ct = g & 15;
        int seg = r & 1, rt = r >> 1;         // rt 0..9
        int pcnt = meta[m];
        if (rt * 256 >= pcnt) return;
        int row0 = meta[4 + m] + rt * 256;
        int k0 = seg * KSEG;

        // staging: chunk-id q -> LDS row q>>3, chunk q&7, source k-chunk
        // (q&7)^((q>>3)&7). Instruction j covers q = j*256 + wave*64 + lane.
        const u16* gA[8]; const u16* gB[4];
        u16* lA[8]; u16* lB[4];
        #pragma unroll
        for (int j = 0; j < 8; ++j) {
            int q = j * 256 + wave * 64 + lane;
            int row = q >> 3, kc = (q & 7) ^ (row & 7);
            gA[j] = A_pack + (size_t)(row0 + row) * KIN + k0 + kc * 8;
            lA[j] = As + q * 8;
        }
        #pragma unroll
        for (int j = 0; j < 4; ++j) {
            int q = j * 256 + wave * 64 + lane;
            int row = q >> 3, kc = (q & 7) ^ (row & 7);
            gB[j] = Wb + ((size_t)m * G4H + ct * 128 + row) * KIN + k0 + kc * 8;
            lB[j] = Bs + q * 8;
        }

        int wm = wave >> 1, wn = wave & 1;    // wave tile: rows wm*128, cols wn*64

        f32x4 acc[8][4];
        #pragma unroll
        for (int i = 0; i < 8; ++i)
            #pragma unroll
            for (int j = 0; j < 4; ++j)
                acc[i][j] = (f32x4){0.f, 0.f, 0.f, 0.f};

        for (int ks = 0; ks < KSEG / 64; ++ks) {
            #pragma unroll
            for (int j = 0; j < 8; ++j) { gl16(gA[j], lA[j]); gA[j] += 64; }
            #pragma unroll
            for (int j = 0; j < 4; ++j) { gl16(gB[j], lB[j]); gB[j] += 64; }
            __syncthreads();
            #pragma unroll
            for (int ks2 = 0; ks2 < 2; ++ks2) {
                int ch = (ks2 * 4 + qd) ^ rsw;
                bf16x8 fb[4];
                #pragma unroll
                for (int tj = 0; tj < 4; ++tj) {
                    int row = wn * 64 + tj * 16 + l15;
                    fb[tj] = *reinterpret_cast<const bf16x8*>(&Bs[row * 64 + ch * 8]);
                }
                #pragma unroll
                for (int ti = 0; ti < 8; ++ti) {
                    int row = wm * 128 + ti * 16 + l15;
                    bf16x8 fa = *reinterpret_cast<const bf16x8*>(&As[row * 64 + ch * 8]);
                    #pragma unroll
                    for (int tj = 0; tj < 4; ++tj)
                        acc[ti][tj] = __builtin_amdgcn_mfma_f32_16x16x32_bf16(fa, fb[tj], acc[ti][tj], 0, 0, 0);
                }
            }
            __syncthreads();
        }

        u16* gout = seg ? gates1 : gates0;
        #pragma unroll
        for (int ti = 0; ti < 8; ++ti) {
            #pragma unroll
            for (int tj = 0; tj < 4; ++tj) {
                int gcol = ct * 128 + wn * 64 + tj * 16 + l15;
                #pragma unroll
                for (int rr = 0; rr < 4; ++rr) {
                    int grow = row0 + wm * 128 + ti * 16 + qd * 4 + rr;
                    gout[(size_t)grow * G4H + gcol] = f2bf(acc[ti][tj][rr]);
                }
            }
        }
    } else {
        // ---------------- log_odds GEMM (64 x 128, K=512) ----------------
        int rtl = id - 1280;                  // 0..127 global slot tile
        int k = meta[136 + rtl];
        if (k < 0) return;
        int r0 = rtl * 64;

        if (tid < 64) sperm[tid] = perm_cat[r0 + tid];
        __syncthreads();

        int rb = tid >> 3;                    // 0..31
        int kc = (tid & 7) ^ (rb & 7);

        // B = Wlin[k] (128 x 64/iter) via gl16 into As
        const u16* gW[4]; u16* lW[4];
        #pragma unroll
        for (int i = 0; i < 4; ++i) {
            gW[i] = Wlin + ((size_t)k * CCH + i * 32 + rb) * HID + kc * 8;
            lW[i] = As + (i * 256 + wave * 64) * 8;
        }
        // A = et rows gathered, f32->bf16 VALU staging into Bs (64 x 64/iter)
        int ar = tid >> 2;                    // 0..63
        int acp = tid & 3;                    // 2 chunks each
        int at = sperm[ar];
        const float* asrc = (at >= 0) ? (et + (size_t)at * HID) : nullptr;

        f32x4 acc[4][2];
        #pragma unroll
        for (int i = 0; i < 4; ++i) {
            acc[i][0] = (f32x4){0.f, 0.f, 0.f, 0.f};
            acc[i][1] = (f32x4){0.f, 0.f, 0.f, 0.f};
        }

        for (int kk = 0; kk < HID; kk += 64) {
            #pragma unroll
            for (int i = 0; i < 4; ++i) { gl16(gW[i], lW[i]); gW[i] += 64; }
            #pragma unroll
            for (int j = 0; j < 2; ++j) {
                int dch = acp * 2 + j;
                int sch = dch ^ (ar & 7);
                u16* dst = &Bs[ar * 64 + dch * 8];
                if (asrc) {
                    const float* s = asrc + kk + sch * 8;
                    store_bf8(dst, *(const float4*)s, *(const float4*)(s + 4));
                } else {
                    *reinterpret_cast<int4*>(dst) = make_int4(0, 0, 0, 0);
                }
            }
            __syncthreads();
            #pragma unroll
            for (int ks2 = 0; ks2 < 2; ++ks2) {
                int ch = (ks2 * 4 + qd) ^ rsw;
                bf16x8 fa[4], fb[2];
                #pragma unroll
                for (int ti = 0; ti < 4; ++ti)
                    fa[ti] = *reinterpret_cast<const bf16x8*>(&Bs[(ti * 16 + l15) * 64 + ch * 8]);
                #pragma unroll
                for (int tj = 0; tj < 2; ++tj)
                    fb[tj] = *reinterpret_cast<const bf16x8*>(&As[(wave * 32 + tj * 16 + l15) * 64 + ch * 8]);
                #pragma unroll
                for (int ti = 0; ti < 4; ++ti)
                    #pragma unroll
                    for (int tj = 0; tj < 2; ++tj)
                        acc[ti][tj] = __builtin_amdgcn_mfma_f32_16x16x32_bf16(fa[ti], fb[tj], acc[ti][tj], 0, 0, 0);
            }
            __syncthreads();
        }

        #pragma unroll
        for (int ti = 0; ti < 4; ++ti) {
            #pragma unroll
            for (int tj = 0; tj < 2; ++tj) {
                int n = wave * 32 + tj * 16 + l15;
                float bias = b_lin[k * CCH + n];
                #pragma unroll
                for (int rr = 0; rr < 4; ++rr) {
                    int row = ti * 16 + qd * 4 + rr;
                    int t = sperm[row];
                    if (t >= 0)
                        out[(size_t)t * CCH + n] = acc[ti][tj][rr] + bias;
                }
            }
        }
    }
}

// ---------------------------------------------------------------------------
// Dispatch 3: LSTM pointwise epilogue; sums the two K-split partials.
// ---------------------------------------------------------------------------
__global__ __launch_bounds__(256) void lstm_epilogue(
    const u16* __restrict__ gates0, const u16* __restrict__ gates1,
    const int* __restrict__ meta,
    const int* __restrict__ inv_ci,
    const float* __restrict__ c,
    const float* __restrict__ b_ih,   // [4,2048]
    const float* __restrict__ b_hh,   // [4,2048]
    float* __restrict__ out)
{
    int idx = blockIdx.x * 256 + threadIdx.x;   // [0, N*512)
    int t = idx >> 9;
    int hh = idx & 511;
    int s = inv_ci[t];
    int m = (s >= meta[5]) + (s >= meta[6]) + (s >= meta[7]);

    const u16* g0 = gates0 + (size_t)s * G4H;
    const u16* g1 = gates1 + (size_t)s * G4H;
    const float* bi = b_ih + (size_t)m * G4H;
    const float* bh = b_hh + (size_t)m * G4H;
    float gi = bf2f(g0[hh])        + bf2f(g1[hh])        + bi[hh]        + bh[hh];
    float gf = bf2f(g0[512 + hh])  + bf2f(g1[512 + hh])  + bi[512 + hh]  + bh[512 + hh];
    float gg = bf2f(g0[1024 + hh]) + bf2f(g1[1024 + hh]) + bi[1024 + hh] + bh[1024 + hh];
    float go = bf2f(g0[1536 + hh]) + bf2f(g1[1536 + hh]) + bi[1536 + hh] + bh[1536 + hh];

    float si = 1.f / (1.f + __expf(-gi));
    float sf = 1.f / (1.f + __expf(-gf));
    float so = 1.f / (1.f + __expf(-go));
    float ct = c[(size_t)t * HID + hh];
    float c2 = sf * ct + si * tanhf(gg);
    float h2 = so * tanhf(c2);

    const size_t o_h2 = (size_t)NTOK * CCH;
    const size_t o_c2 = o_h2 + (size_t)NTOK * HID;
    out[o_h2 + (size_t)t * HID + hh] = h2;
    out[o_c2 + (size_t)t * HID + hh] = c2;
}

// ---------------------------------------------------------------------------
extern "C" void kernel_launch(void* const* d_in, const int* in_sizes, int n_in,
                              void* d_out, int out_size, void* d_ws, size_t ws_size,
                              hipStream_t stream) {
    const float* et    = (const float*)d_in[0];
    const float* x     = (const float*)d_in[1];
    const float* h     = (const float*)d_in[2];
    const float* c     = (const float*)d_in[3];
    const int*   cat   = (const int*)d_in[4];
    const int*   ci    = (const int*)d_in[5];
    const float* W_lin = (const float*)d_in[6];
    const float* b_lin = (const float*)d_in[7];
    const float* W_ih  = (const float*)d_in[8];
    const float* W_hh  = (const float*)d_in[9];
    const float* b_ih  = (const float*)d_in[10];
    const float* b_hh  = (const float*)d_in[11];
    float* out = (float*)d_out;

    char* ws = (char*)d_ws;
    int* meta     = (int*)ws;                         // 512 ints (incl. LUT)
    int* perm_ci  = (int*)(ws + 2048);                // 5120 ints -> 22528
    int* perm_cat = (int*)(ws + 22528);               // 8192 ints -> 55296
    int* inv_ci   = (int*)(ws + 55296);               // 4096 ints -> 71680
    u16* A_pack   = (u16*)(ws + 71680);               // 5120*1536*2 -> 15800320
    u16* Wb       = (u16*)(ws + 15800320);            // -> 40966144
    u16* Wlin     = (u16*)(ws + 40966144);            // -> 49354752
    u16* gates0   = (u16*)(ws + 49354752);            // 5120*2048*2 -> 70326272
    u16* gates1   = (u16*)(ws + 70326272);            // -> 91297792 (~91.3 MB)

    build_perm<<<1, 1024, 0, stream>>>(ci, cat, meta, perm_ci, inv_ci, perm_cat);

    fat_pack<<<PK_BLOCKS, 256, 0, stream>>>(x, h, W_ih, W_hh, W_lin, perm_ci,
                                            A_pack, Wb, Wlin);

    mega_gemm<<<1280 + 128, 256, 0, stream>>>(A_pack, Wb, Wlin, et, b_lin, meta,
                                              perm_cat, gates0, gates1, out);

    lstm_epilogue<<<(NTOK * HID) / 256, 256, 0, stream>>>(gates0, gates1, meta,
                                                          inv_ci, c, b_ih, b_hh, out);
}